// Round 6
// baseline (246.422 us; speedup 1.0000x reference)
//
#include <hip/hip_runtime.h>
#include <math.h>

#define DEV __device__ __forceinline__

// R5: back to SCALAR fp32, 1 row/thread. Evidence: CDNA4 fp32 peak 157.3 TF
// IS the scalar v_fma_f32 rate (SIMD-32); v_pk_fma_f32 is FLOP-neutral
// (~4cyc vs 2cyc) and only doubled register liveness (R4: ~176 unified
// regs/wave -> 2.9 waves/SIMD, VALUBusy 57%). Scalar liveness ~85 regs.
//
// amdgpu_waves_per_eu(4,4): clamp BOTH min and max. __launch_bounds__'s 2nd
// arg is only a min -> allocator still targeted 8 waves/EU and parked live
// state in AGPRs with v_accvgpr churn (R1: 36 VGPRs for ~80 live floats).
// Budget 512/4 = 128 VGPRs fits all liveness with zero AGPR/spill traffic.

// k-outer linear layer: in[k] read once per k; DOUT independent acc chains
// (dep distance >= 6 >= FMA latency -> good single-wave ILP).
template <int DIN, int DOUT>
DEV void lin(const float* __restrict__ w, const float* __restrict__ b,
             const float* in, float* out) {
#pragma unroll
    for (int o = 0; o < DOUT; ++o) out[o] = b[o];
#pragma unroll
    for (int k = 0; k < DIN; ++k) {
        float xk = in[k];
#pragma unroll
        for (int o = 0; o < DOUT; ++o)
            out[o] = fmaf(xk, w[o * DIN + k], out[o]);
    }
}

// Accumulator starts at bias + skip (fused decoder skip-add).
template <int DIN, int DOUT>
DEV void lin_skip(const float* __restrict__ w, const float* __restrict__ b,
                  const float* in, const float* skip, float* out) {
#pragma unroll
    for (int o = 0; o < DOUT; ++o) out[o] = b[o] + skip[o];
#pragma unroll
    for (int k = 0; k < DIN; ++k) {
        float xk = in[k];
#pragma unroll
        for (int o = 0; o < DOUT; ++o)
            out[o] = fmaf(xk, w[o * DIN + k], out[o]);
    }
}

template <int N>
DEV void relu_ip(float* v) {
#pragma unroll
    for (int k = 0; k < N; ++k) v[k] = fmaxf(v[k], 0.0f);
}

__global__ void __launch_bounds__(256)
__attribute__((amdgpu_waves_per_eu(4, 4)))
csnet14_kernel(const float* __restrict__ x,
               const float* __restrict__ w1,  const float* __restrict__ b1,
               const float* __restrict__ w2,  const float* __restrict__ b2,
               const float* __restrict__ w3,  const float* __restrict__ b3,
               const float* __restrict__ w4,  const float* __restrict__ b4,
               const float* __restrict__ w5,  const float* __restrict__ b5,
               const float* __restrict__ w6,  const float* __restrict__ b6,
               const float* __restrict__ w7,  const float* __restrict__ b7,
               const float* __restrict__ w8,  const float* __restrict__ b8,
               const float* __restrict__ w9,  const float* __restrict__ b9,
               const float* __restrict__ w10, const float* __restrict__ b10,
               const float* __restrict__ w11, const float* __restrict__ b11,
               const float* __restrict__ w12, const float* __restrict__ b12,
               const float* __restrict__ w13, const float* __restrict__ b13,
               const float* __restrict__ w14, const float* __restrict__ b14,
               float* __restrict__ out, int n) {
    int i = blockIdx.x * blockDim.x + threadIdx.x;
    if (i >= n) return;

    // One 12-float row: 3x float4 (48 B, 16B-aligned).
    const float4* xr = reinterpret_cast<const float4*>(x + (size_t)i * 12);
    float4 v0 = xr[0];
    float4 v1 = xr[1];
    float4 v2 = xr[2];
    float h0[12] = {v0.x, v0.y, v0.z, v0.w,
                    v1.x, v1.y, v1.z, v1.w,
                    v2.x, v2.y, v2.z, v2.w};

    // Encoder: fc1..fc6, save post-ReLU identities.
    float id1[12]; lin<12, 12>(w1, b1, h0,  id1); relu_ip<12>(id1);
    float id2[11]; lin<12, 11>(w2, b2, id1, id2); relu_ip<11>(id2);
    float id3[10]; lin<11, 10>(w3, b3, id2, id3); relu_ip<10>(id3);
    float id4[9];  lin<10,  9>(w4, b4, id3, id4); relu_ip<9>(id4);
    float id5[8];  lin< 9,  8>(w5, b5, id4, id5); relu_ip<8>(id5);
    float id6[7];  lin< 8,  7>(w6, b6, id5, id6); relu_ip<7>(id6);

    // Bottleneck fc7.
    float t7[6];   lin< 7,  6>(w7, b7, id6, t7);  relu_ip<6>(t7);

    // Decoder: fc8..fc13, skip fused into accumulator init.
    float t8[7];   lin_skip< 6,  7>(w8,  b8,  t7,  id6, t8);  relu_ip<7>(t8);
    float t9[8];   lin_skip< 7,  8>(w9,  b9,  t8,  id5, t9);  relu_ip<8>(t9);
    float t10[9];  lin_skip< 8,  9>(w10, b10, t9,  id4, t10); relu_ip<9>(t10);
    float t11[10]; lin_skip< 9, 10>(w11, b11, t10, id3, t11); relu_ip<10>(t11);
    float t12[11]; lin_skip<10, 11>(w12, b12, t11, id2, t12); relu_ip<11>(t12);
    float t13[12]; lin_skip<11, 12>(w13, b13, t12, id1, t13); relu_ip<12>(t13);

    // fc14 (12 -> 2) + softmax.
    float l[2];    lin<12,  2>(w14, b14, t13, l);
    float m  = fmaxf(l[0], l[1]);
    float e0 = __expf(l[0] - m);
    float e1 = __expf(l[1] - m);
    float inv = __builtin_amdgcn_rcpf(e0 + e1);

    float2 o;
    o.x = e0 * inv;
    o.y = e1 * inv;
    reinterpret_cast<float2*>(out)[i] = o;
}

extern "C" void kernel_launch(void* const* d_in, const int* in_sizes, int n_in,
                              void* d_out, int out_size, void* d_ws, size_t ws_size,
                              hipStream_t stream) {
    const float* x   = (const float*)d_in[0];
    const float* w1  = (const float*)d_in[1];  const float* b1  = (const float*)d_in[2];
    const float* w2  = (const float*)d_in[3];  const float* b2  = (const float*)d_in[4];
    const float* w3  = (const float*)d_in[5];  const float* b3  = (const float*)d_in[6];
    const float* w4  = (const float*)d_in[7];  const float* b4  = (const float*)d_in[8];
    const float* w5  = (const float*)d_in[9];  const float* b5  = (const float*)d_in[10];
    const float* w6  = (const float*)d_in[11]; const float* b6  = (const float*)d_in[12];
    const float* w7  = (const float*)d_in[13]; const float* b7  = (const float*)d_in[14];
    const float* w8  = (const float*)d_in[15]; const float* b8  = (const float*)d_in[16];
    const float* w9  = (const float*)d_in[17]; const float* b9  = (const float*)d_in[18];
    const float* w10 = (const float*)d_in[19]; const float* b10 = (const float*)d_in[20];
    const float* w11 = (const float*)d_in[21]; const float* b11 = (const float*)d_in[22];
    const float* w12 = (const float*)d_in[23]; const float* b12 = (const float*)d_in[24];
    const float* w13 = (const float*)d_in[25]; const float* b13 = (const float*)d_in[26];
    const float* w14 = (const float*)d_in[27]; const float* b14 = (const float*)d_in[28];
    float* out = (float*)d_out;

    const int n = in_sizes[0] / 12;  // 2,000,000 rows
    dim3 block(256);
    dim3 grid((n + 255) / 256);
    csnet14_kernel<<<grid, block, 0, stream>>>(
        x, w1, b1, w2, b2, w3, b3, w4, b4, w5, b5, w6, b6, w7, b7,
        w8, b8, w9, b9, w10, b10, w11, b11, w12, b12, w13, b13, w14, b14,
        out, n);
}